// Round 9
// baseline (599.746 us; speedup 1.0000x reference)
//
#include <hip/hip_runtime.h>
#include <float.h>

#define BATCH 4

typedef _Float16 half8 __attribute__((ext_vector_type(8)));
typedef float f32x16 __attribute__((ext_vector_type(16)));
typedef float f32x2 __attribute__((ext_vector_type(2)));

// ================= MFMA path =================
// D[i,j] = |p_i|^2 + |q_j|^2 - 2 p.q  via K=13 fp16 slots (exact split):
//  A[p] = [hx,hy,hz, hx,hy,hz, ex,ey,ez, ps_h, ps_e, 1, 1, 0,0,0]
//  B[q] = [-2hx,-2hy,-2hz, -2ex,-2ey,-2ez, -2hx,-2hy,-2hz, 1, 1, qs_h, qs_e, 0,0,0]
// fp16*fp16 products exact in fp32 accumulator. Verified R7/R8: absmax 4e-3.

__global__ void prep_fp16(const float* __restrict__ x1, const float* __restrict__ x2,
                          _Float16* __restrict__ pa1, _Float16* __restrict__ pb1,
                          _Float16* __restrict__ pa2, _Float16* __restrict__ pb2,
                          float* __restrict__ out, int n1, int n2, int outn) {
    const int i = blockIdx.x * blockDim.x + threadIdx.x;
    const _Float16 one = (_Float16)1.0f, zro = (_Float16)0.0f;

    #pragma unroll
    for (int which = 0; which < 2; ++which) {
        const int n = which ? n2 : n1;
        if (i >= n) continue;
        const float* xp = (which ? x2 : x1) + 3 * (size_t)i;
        _Float16* pa = (which ? pa2 : pa1) + 16 * (size_t)i;
        _Float16* pb = (which ? pb2 : pb1) + 16 * (size_t)i;

        const float x = xp[0], y = xp[1], z = xp[2];
        const _Float16 hx = (_Float16)x, hy = (_Float16)y, hz = (_Float16)z;
        const _Float16 ex = (_Float16)(x - (float)hx);
        const _Float16 ey = (_Float16)(y - (float)hy);
        const _Float16 ez = (_Float16)(z - (float)hz);
        const float ps = fmaf(x, x, fmaf(y, y, z * z));
        const _Float16 ph = (_Float16)ps;
        const _Float16 pe = (_Float16)(ps - (float)ph);
        const _Float16 tx = (_Float16)(-2.0f * (float)hx);
        const _Float16 ty = (_Float16)(-2.0f * (float)hy);
        const _Float16 tz = (_Float16)(-2.0f * (float)hz);
        const _Float16 ux = (_Float16)(-2.0f * (float)ex);
        const _Float16 uy = (_Float16)(-2.0f * (float)ey);
        const _Float16 uz = (_Float16)(-2.0f * (float)ez);

        const half8 a0 = (half8){hx, hy, hz, hx, hy, hz, ex, ey};
        const half8 a1 = (half8){ez, ph, pe, one, one, zro, zro, zro};
        const half8 b0 = (half8){tx, ty, tz, ux, uy, uz, tx, ty};
        const half8 b1 = (half8){tz, one, one, ph, pe, zro, zro, zro};

        *(half8*)(pa)     = a0;   // 16B vector stores, 32B-aligned
        *(half8*)(pa + 8) = a1;
        *(half8*)(pb)     = b0;
        *(half8*)(pb + 8) = b1;
    }
    if (i < outn) out[i] = FLT_MAX;
}

// Min-reduce over the 32 lanes of each 32-lane half, pure-VALU DPP.
// Result valid in lanes 16..31 and 48..63.  (Verified R8.)
__device__ inline float colmin32_dpp(float v) {
    int x = __builtin_bit_cast(int, v);
    x = __builtin_amdgcn_update_dpp(x, x, 0x121, 0xF, 0xF, false);  // row_ror:1
    v = fminf(v, __builtin_bit_cast(float, x));
    x = __builtin_bit_cast(int, v);
    x = __builtin_amdgcn_update_dpp(x, x, 0x122, 0xF, 0xF, false);  // row_ror:2
    v = fminf(v, __builtin_bit_cast(float, x));
    x = __builtin_bit_cast(int, v);
    x = __builtin_amdgcn_update_dpp(x, x, 0x124, 0xF, 0xF, false);  // row_ror:4
    v = fminf(v, __builtin_bit_cast(float, x));
    x = __builtin_bit_cast(int, v);
    x = __builtin_amdgcn_update_dpp(x, x, 0x128, 0xF, 0xF, false);  // row_ror:8
    v = fminf(v, __builtin_bit_cast(float, x));
    x = __builtin_bit_cast(int, v);
    x = __builtin_amdgcn_update_dpp(x, x, 0x142, 0xA, 0xF, false);  // row_bcast:15 rows 1,3
    v = fminf(v, __builtin_bit_cast(float, x));
    return v;
}

// Block: 4 waves x IT=2 i-tiles of 32 rows = 256 rows. Sweeps a j-segment
// (N/NJ cols) in LDS stages of 256 cols = 8 j-tiles, double-buffered with
// ONE barrier per stage; next stage's global loads issued before compute.
// Layouts (verified R8):
//  A/B frag: row/col = lane&31, k = 8*(lane>>5)..  (16B per lane)
//  D: col = lane&31, row = (e&3) + 8*(e>>2) + 4*(lane>>5)
template<int NJ>
__global__ __launch_bounds__(256, 4) void chamfer_mfma32(
        const _Float16* __restrict__ pa1, const _Float16* __restrict__ pb1,
        const _Float16* __restrict__ pa2, const _Float16* __restrict__ pb2,
        float* __restrict__ out, int N) {
    constexpr int IT = 2;
    __shared__ uint4 sB[2][512];   // 2 x 8 KiB

    const int tid  = threadIdx.x;
    const int lane = tid & 63;
    const int w    = tid >> 6;

    int bid = blockIdx.x;
    const int RB      = N / 256;
    const int per_dir = BATCH * RB * NJ;
    const int dir = bid / per_dir;   bid %= per_dir;
    const int b   = bid / (RB * NJ); bid %= (RB * NJ);
    const int rb  = bid / NJ;
    const int js  = bid % NJ;

    const _Float16* pa = dir ? pa2 : pa1;
    const _Float16* pb = dir ? pb1 : pb2;
    float* outd = out + (size_t)dir * BATCH * N + (size_t)b * N;

    const int rowbase = rb * 256 + w * 64;
    const uint4* ga = (const uint4*)pa;
    half8 af[IT];
    #pragma unroll
    for (int it = 0; it < IT; ++it) {
        const int row = rowbase + it * 32 + (lane & 31);
        af[it] = __builtin_bit_cast(half8, ga[(size_t)(b * N + row) * 2 + (lane >> 5)]);
    }

    f32x16 rmin[IT];
    #pragma unroll
    for (int it = 0; it < IT; ++it)
        #pragma unroll
        for (int e = 0; e < 16; ++e)
            rmin[it][e] = FLT_MAX;
    f32x16 cz;
    #pragma unroll
    for (int e = 0; e < 16; ++e) cz[e] = 0.0f;

    const int jseg   = N / NJ;
    const int stages = jseg / 256;
    const uint4* gb  = (const uint4*)pb;
    const int t = tid >> 5, col = tid & 31;

    // prologue: stage 0 into buf 0
    {
        const size_t q = (size_t)(b * N + js * jseg + tid) * 2;
        sB[0][t * 64 + col]      = gb[q];
        sB[0][t * 64 + 32 + col] = gb[q + 1];
    }
    __syncthreads();

    for (int s = 0; s < stages; ++s) {
        const int cur = s & 1;
        uint4 v0, v1;
        if (s + 1 < stages) {               // issue next stage's loads early
            const size_t q = (size_t)(b * N + js * jseg + (s + 1) * 256 + tid) * 2;
            v0 = gb[q]; v1 = gb[q + 1];
        }

        #pragma unroll
        for (int p = 0; p < 4; ++p) {
            const half8 b0 = __builtin_bit_cast(half8, sB[cur][(2 * p)     * 64 + lane]);
            const half8 b1 = __builtin_bit_cast(half8, sB[cur][(2 * p + 1) * 64 + lane]);
            #pragma unroll
            for (int it = 0; it < IT; ++it) {
                const f32x16 d0 = __builtin_amdgcn_mfma_f32_32x32x16_f16(af[it], b0, cz, 0, 0, 0);
                const f32x16 d1 = __builtin_amdgcn_mfma_f32_32x32x16_f16(af[it], b1, cz, 0, 0, 0);
                #pragma unroll
                for (int e = 0; e < 16; ++e)
                    rmin[it][e] = fminf(fminf(rmin[it][e], d0[e]), d1[e]);  // v_min3_f32
            }
        }

        if (s + 1 < stages) {               // write other buffer; safe pre-barrier
            sB[cur ^ 1][t * 64 + col]      = v0;
            sB[cur ^ 1][t * 64 + 32 + col] = v1;
        }
        __syncthreads();                    // one barrier per stage
    }

    #pragma unroll
    for (int it = 0; it < IT; ++it) {
        #pragma unroll
        for (int e = 0; e < 16; ++e)
            rmin[it][e] = colmin32_dpp(rmin[it][e]);
        if ((lane & 31) == 16) {
            const int r0 = rowbase + it * 32 + 4 * (lane >> 5);
            #pragma unroll
            for (int e = 0; e < 16; ++e) {
                const float v = fmaxf(rmin[it][e], 0.0f);   // >=0 keeps int-min order
                atomicMin((int*)&outd[r0 + (e & 3) + 8 * (e >> 2)], __float_as_int(v));
            }
        }
    }
}

// ================= fallback: R6 pk-fma path =================
__global__ void chamfer_prep(const float* __restrict__ xyz1,
                             const float* __restrict__ xyz2,
                             float4* __restrict__ pk1,
                             float4* __restrict__ pk2,
                             float* __restrict__ out,
                             int n1, int n2, int out_n) {
    int i = blockIdx.x * blockDim.x + threadIdx.x;
    if (i < n1) {
        float x = xyz1[3 * (size_t)i], y = xyz1[3 * (size_t)i + 1], z = xyz1[3 * (size_t)i + 2];
        pk1[i] = make_float4(-2.f * x, -2.f * y, -2.f * z, fmaf(x, x, fmaf(y, y, z * z)));
    }
    if (i < n2) {
        float x = xyz2[3 * (size_t)i], y = xyz2[3 * (size_t)i + 1], z = xyz2[3 * (size_t)i + 2];
        pk2[i] = make_float4(-2.f * x, -2.f * y, -2.f * z, fmaf(x, x, fmaf(y, y, z * z)));
    }
    if (i < out_n) out[i] = FLT_MAX;
}

template<int TPB, int CHUNK, int P>
__global__ __launch_bounds__(TPB) void chamfer_fused(
        const float* __restrict__ xyz1, const float* __restrict__ xyz2,
        const float4* __restrict__ pk1, const float4* __restrict__ pk2,
        float* __restrict__ out, int N, int M, int blocks_dir0) {
    __shared__ float4 s[CHUNK];
    int bid = blockIdx.x;
    const int dir = (bid >= blocks_dir0) ? 1 : 0;
    if (dir) bid -= blocks_dir0;
    const int Nsrc = dir ? M : N;
    const int Mdst = dir ? N : M;
    const float* src   = dir ? xyz2 : xyz1;
    const float4* dstp = dir ? pk1  : pk2;
    float* outd        = dir ? (out + (size_t)BATCH * N) : out;
    const int YT = Nsrc / (TPB * P);
    const int Z  = Mdst / CHUNK;
    const int b  = bid / (YT * Z);
    const int r  = bid % (YT * Z);
    const int yt = r / Z;
    const int z  = r % Z;
    const float4* dchunk = dstp + (size_t)b * Mdst + (size_t)z * CHUNK;
    for (int t = threadIdx.x; t < CHUNK / 2; t += TPB) {
        const float4 q0 = dchunk[2 * t];
        const float4 q1 = dchunk[2 * t + 1];
        s[2 * t]     = make_float4(q0.x, q1.x, q0.y, q1.y);
        s[2 * t + 1] = make_float4(q0.z, q1.z, q0.w, q1.w);
    }
    const int i0 = yt * (TPB * P) + threadIdx.x;
    f32x2 px[P], py[P], pz[P];
    float psq[P], m[P];
    #pragma unroll
    for (int k = 0; k < P; ++k) {
        const int i = i0 + k * TPB;
        const float* p = src + ((size_t)b * Nsrc + i) * 3;
        const float x = p[0], y = p[1], zc = p[2];
        px[k] = (f32x2){x, x}; py[k] = (f32x2){y, y}; pz[k] = (f32x2){zc, zc};
        psq[k] = fmaf(x, x, fmaf(y, y, zc * zc));
        m[k] = FLT_MAX;
    }
    __syncthreads();
    #pragma unroll 8
    for (int jj = 0; jj < CHUNK / 2; ++jj) {
        const float4 A = s[2 * jj];
        const float4 B = s[2 * jj + 1];
        const f32x2 xq = (f32x2){A.x, A.y};
        const f32x2 yq = (f32x2){A.z, A.w};
        const f32x2 zq = (f32x2){B.x, B.y};
        const f32x2 wq = (f32x2){B.z, B.w};
        #pragma unroll
        for (int k = 0; k < P; ++k) {
            const f32x2 e = __builtin_elementwise_fma(xq, px[k],
                             __builtin_elementwise_fma(yq, py[k],
                              __builtin_elementwise_fma(zq, pz[k], wq)));
            m[k] = fminf(fminf(m[k], e.x), e.y);
        }
    }
    #pragma unroll
    for (int k = 0; k < P; ++k) {
        const int i = i0 + k * TPB;
        const float d = fmaxf(psq[k] + m[k], 0.0f);
        atomicMin((int*)&outd[(size_t)b * Nsrc + i], __float_as_int(d));
    }
}

extern "C" void kernel_launch(void* const* d_in, const int* in_sizes, int n_in,
                              void* d_out, int out_size, void* d_ws, size_t ws_size,
                              hipStream_t stream) {
    const float* xyz1 = (const float*)d_in[0];
    const float* xyz2 = (const float*)d_in[1];
    float* out = (float*)d_out;

    const int N = in_sizes[0] / (BATCH * 3);  // 8192
    const int M = in_sizes[1] / (BATCH * 3);  // 8192
    const int n1 = BATCH * N, n2 = BATCH * M;

    constexpr int TPB = 256;
    constexpr int NJ = 8;

    const size_t need16 = ((size_t)n1 + (size_t)n2) * 64;  // A+B fp16 forms
    const bool mfma_ok = (N == M) && (N % (NJ * 256) == 0) && (ws_size >= need16);

    if (mfma_ok) {
        _Float16* pa1 = (_Float16*)d_ws;
        _Float16* pb1 = pa1 + (size_t)n1 * 16;
        _Float16* pa2 = pb1 + (size_t)n1 * 16;
        _Float16* pb2 = pa2 + (size_t)n2 * 16;
        int prep_n = out_size > n1 ? out_size : n1;
        if (n2 > prep_n) prep_n = n2;
        prep_fp16<<<(prep_n + TPB - 1) / TPB, TPB, 0, stream>>>(
            xyz1, xyz2, pa1, pb1, pa2, pb2, out, n1, n2, out_size);

        const int grid = 2 * BATCH * (N / 256) * NJ;   // 2048
        chamfer_mfma32<NJ><<<grid, TPB, 0, stream>>>(pa1, pb1, pa2, pb2, out, N);
        return;
    }

    // fallback: R6 pk-fma path
    constexpr int CHUNK = 128;
    constexpr int P = 8;
    const size_t need = ((size_t)n1 + (size_t)n2) * sizeof(float4);
    if (ws_size >= need && (N % (TPB * P) == 0) && (M % (TPB * P) == 0) &&
        (N % CHUNK == 0) && (M % CHUNK == 0)) {
        float4* pk1 = (float4*)d_ws;
        float4* pk2 = pk1 + n1;
        int prep_n = out_size > n1 ? out_size : n1;
        if (n2 > prep_n) prep_n = n2;
        chamfer_prep<<<(prep_n + TPB - 1) / TPB, TPB, 0, stream>>>(
            xyz1, xyz2, pk1, pk2, out, n1, n2, out_size);
        const int blocks_dir0 = BATCH * (N / (TPB * P)) * (M / CHUNK);
        const int blocks_dir1 = BATCH * (M / (TPB * P)) * (N / CHUNK);
        chamfer_fused<TPB, CHUNK, P><<<blocks_dir0 + blocks_dir1, TPB, 0, stream>>>(
            xyz1, xyz2, pk1, pk2, out, N, M, blocks_dir0);
    }
}

// Round 10
// 78.285 us; speedup vs baseline: 7.6610x; 7.6610x over previous
//
#include <hip/hip_runtime.h>
#include <float.h>

#define BATCH 4

typedef _Float16 half8 __attribute__((ext_vector_type(8)));
typedef float f32x16 __attribute__((ext_vector_type(16)));
typedef float f32x2 __attribute__((ext_vector_type(2)));

// ================= MFMA path =================
// D[i,j] = |p_i|^2 + |q_j|^2 - 2 p.q  via K=13 fp16 slots (exact split):
//  A[p] = [hx,hy,hz, hx,hy,hz, ex,ey,ez, ps_h, ps_e, 1, 1, 0,0,0]
//  B[q] = [-2hx,-2hy,-2hz, -2ex,-2ey,-2ez, -2hx,-2hy,-2hz, 1, 1, qs_h, qs_e, 0,0,0]
// fp16*fp16 products exact in fp32 accumulator. Verified R7/R8/R9.

__global__ void prep_fp16(const float* __restrict__ x1, const float* __restrict__ x2,
                          _Float16* __restrict__ pa1, _Float16* __restrict__ pb1,
                          _Float16* __restrict__ pa2, _Float16* __restrict__ pb2,
                          float* __restrict__ out, int n1, int n2, int outn) {
    const int i = blockIdx.x * blockDim.x + threadIdx.x;
    const _Float16 one = (_Float16)1.0f, zro = (_Float16)0.0f;

    #pragma unroll
    for (int which = 0; which < 2; ++which) {
        const int n = which ? n2 : n1;
        if (i >= n) continue;
        const float* xp = (which ? x2 : x1) + 3 * (size_t)i;
        _Float16* pa = (which ? pa2 : pa1) + 16 * (size_t)i;
        _Float16* pb = (which ? pb2 : pb1) + 16 * (size_t)i;

        const float x = xp[0], y = xp[1], z = xp[2];
        const _Float16 hx = (_Float16)x, hy = (_Float16)y, hz = (_Float16)z;
        const _Float16 ex = (_Float16)(x - (float)hx);
        const _Float16 ey = (_Float16)(y - (float)hy);
        const _Float16 ez = (_Float16)(z - (float)hz);
        const float ps = fmaf(x, x, fmaf(y, y, z * z));
        const _Float16 ph = (_Float16)ps;
        const _Float16 pe = (_Float16)(ps - (float)ph);
        const _Float16 tx = (_Float16)(-2.0f * (float)hx);
        const _Float16 ty = (_Float16)(-2.0f * (float)hy);
        const _Float16 tz = (_Float16)(-2.0f * (float)hz);
        const _Float16 ux = (_Float16)(-2.0f * (float)ex);
        const _Float16 uy = (_Float16)(-2.0f * (float)ey);
        const _Float16 uz = (_Float16)(-2.0f * (float)ez);

        const half8 a0 = (half8){hx, hy, hz, hx, hy, hz, ex, ey};
        const half8 a1 = (half8){ez, ph, pe, one, one, zro, zro, zro};
        const half8 b0 = (half8){tx, ty, tz, ux, uy, uz, tx, ty};
        const half8 b1 = (half8){tz, one, one, ph, pe, zro, zro, zro};

        *(half8*)(pa)     = a0;   // 16B vector stores
        *(half8*)(pa + 8) = a1;
        *(half8*)(pb)     = b0;
        *(half8*)(pb + 8) = b1;
    }
    if (i < outn) out[i] = FLT_MAX;
}

// Min-reduce over the 32 lanes of each 32-lane half, pure-VALU DPP.
// Result valid in lanes 16..31 and 48..63.  (Verified R8.)
__device__ inline float colmin32_dpp(float v) {
    int x = __builtin_bit_cast(int, v);
    x = __builtin_amdgcn_update_dpp(x, x, 0x121, 0xF, 0xF, false);  // row_ror:1
    v = fminf(v, __builtin_bit_cast(float, x));
    x = __builtin_bit_cast(int, v);
    x = __builtin_amdgcn_update_dpp(x, x, 0x122, 0xF, 0xF, false);  // row_ror:2
    v = fminf(v, __builtin_bit_cast(float, x));
    x = __builtin_bit_cast(int, v);
    x = __builtin_amdgcn_update_dpp(x, x, 0x124, 0xF, 0xF, false);  // row_ror:4
    v = fminf(v, __builtin_bit_cast(float, x));
    x = __builtin_bit_cast(int, v);
    x = __builtin_amdgcn_update_dpp(x, x, 0x128, 0xF, 0xF, false);  // row_ror:8
    v = fminf(v, __builtin_bit_cast(float, x));
    x = __builtin_bit_cast(int, v);
    x = __builtin_amdgcn_update_dpp(x, x, 0x142, 0xA, 0xF, false);  // row_bcast:15 rows 1,3
    v = fminf(v, __builtin_bit_cast(float, x));
    return v;
}

// Block: 4 waves x IT=2 i-tiles of 32 rows = 256 rows. Sweeps a j-segment
// (N/NJ cols) in LDS stages of 256 cols = 8 j-tiles, double-buffered with
// ONE barrier per stage; next stage's global loads issued before compute.
// NOTE: plain __launch_bounds__(256) — R5 and R9 both proved that any
// min-waves arg register-starves this kernel (cap ~ 256/arg VGPRs) and
// spills the f32x16 accumulators to scratch (600 us, 880MB fetch).
// Layouts (verified R8):
//  A/B frag: row/col = lane&31, k = 8*(lane>>5)..  (16B per lane)
//  D: col = lane&31, row = (e&3) + 8*(e>>2) + 4*(lane>>5)
template<int NJ>
__global__ __launch_bounds__(256) void chamfer_mfma32(
        const _Float16* __restrict__ pa1, const _Float16* __restrict__ pb1,
        const _Float16* __restrict__ pa2, const _Float16* __restrict__ pb2,
        float* __restrict__ out, int N) {
    constexpr int IT = 2;
    __shared__ uint4 sB[2][512];   // 2 x 8 KiB

    const int tid  = threadIdx.x;
    const int lane = tid & 63;
    const int w    = tid >> 6;

    int bid = blockIdx.x;
    const int RB      = N / 256;
    const int per_dir = BATCH * RB * NJ;
    const int dir = bid / per_dir;   bid %= per_dir;
    const int b   = bid / (RB * NJ); bid %= (RB * NJ);
    const int rb  = bid / NJ;
    const int js  = bid % NJ;

    const _Float16* pa = dir ? pa2 : pa1;
    const _Float16* pb = dir ? pb1 : pb2;
    float* outd = out + (size_t)dir * BATCH * N + (size_t)b * N;

    const int rowbase = rb * 256 + w * 64;
    const uint4* ga = (const uint4*)pa;
    half8 af[IT];
    #pragma unroll
    for (int it = 0; it < IT; ++it) {
        const int row = rowbase + it * 32 + (lane & 31);
        af[it] = __builtin_bit_cast(half8, ga[(size_t)(b * N + row) * 2 + (lane >> 5)]);
    }

    f32x16 rmin[IT];
    #pragma unroll
    for (int it = 0; it < IT; ++it)
        #pragma unroll
        for (int e = 0; e < 16; ++e)
            rmin[it][e] = FLT_MAX;
    f32x16 cz;
    #pragma unroll
    for (int e = 0; e < 16; ++e) cz[e] = 0.0f;

    const int jseg   = N / NJ;
    const int stages = jseg / 256;
    const uint4* gb  = (const uint4*)pb;
    const int t = tid >> 5, col = tid & 31;

    // prologue: stage 0 into buf 0
    {
        const size_t q = (size_t)(b * N + js * jseg + tid) * 2;
        sB[0][t * 64 + col]      = gb[q];
        sB[0][t * 64 + 32 + col] = gb[q + 1];
    }
    __syncthreads();

    for (int s = 0; s < stages; ++s) {
        const int cur = s & 1;
        uint4 v0, v1;
        if (s + 1 < stages) {               // issue next stage's loads early
            const size_t q = (size_t)(b * N + js * jseg + (s + 1) * 256 + tid) * 2;
            v0 = gb[q]; v1 = gb[q + 1];
        }

        #pragma unroll
        for (int p = 0; p < 4; ++p) {
            const half8 b0 = __builtin_bit_cast(half8, sB[cur][(2 * p)     * 64 + lane]);
            const half8 b1 = __builtin_bit_cast(half8, sB[cur][(2 * p + 1) * 64 + lane]);
            #pragma unroll
            for (int it = 0; it < IT; ++it) {
                const f32x16 d0 = __builtin_amdgcn_mfma_f32_32x32x16_f16(af[it], b0, cz, 0, 0, 0);
                const f32x16 d1 = __builtin_amdgcn_mfma_f32_32x32x16_f16(af[it], b1, cz, 0, 0, 0);
                #pragma unroll
                for (int e = 0; e < 16; ++e)
                    rmin[it][e] = fminf(fminf(rmin[it][e], d0[e]), d1[e]);  // v_min3_f32
            }
        }

        if (s + 1 < stages) {               // write other buffer; safe pre-barrier
            sB[cur ^ 1][t * 64 + col]      = v0;
            sB[cur ^ 1][t * 64 + 32 + col] = v1;
        }
        __syncthreads();                    // one barrier per stage
    }

    #pragma unroll
    for (int it = 0; it < IT; ++it) {
        #pragma unroll
        for (int e = 0; e < 16; ++e)
            rmin[it][e] = colmin32_dpp(rmin[it][e]);
        if ((lane & 31) == 16) {
            const int r0 = rowbase + it * 32 + 4 * (lane >> 5);
            #pragma unroll
            for (int e = 0; e < 16; ++e) {
                const float v = fmaxf(rmin[it][e], 0.0f);   // >=0 keeps int-min order
                atomicMin((int*)&outd[r0 + (e & 3) + 8 * (e >> 2)], __float_as_int(v));
            }
        }
    }
}

// ================= fallback: R6 pk-fma path =================
__global__ void chamfer_prep(const float* __restrict__ xyz1,
                             const float* __restrict__ xyz2,
                             float4* __restrict__ pk1,
                             float4* __restrict__ pk2,
                             float* __restrict__ out,
                             int n1, int n2, int out_n) {
    int i = blockIdx.x * blockDim.x + threadIdx.x;
    if (i < n1) {
        float x = xyz1[3 * (size_t)i], y = xyz1[3 * (size_t)i + 1], z = xyz1[3 * (size_t)i + 2];
        pk1[i] = make_float4(-2.f * x, -2.f * y, -2.f * z, fmaf(x, x, fmaf(y, y, z * z)));
    }
    if (i < n2) {
        float x = xyz2[3 * (size_t)i], y = xyz2[3 * (size_t)i + 1], z = xyz2[3 * (size_t)i + 2];
        pk2[i] = make_float4(-2.f * x, -2.f * y, -2.f * z, fmaf(x, x, fmaf(y, y, z * z)));
    }
    if (i < out_n) out[i] = FLT_MAX;
}

template<int TPB, int CHUNK, int P>
__global__ __launch_bounds__(TPB) void chamfer_fused(
        const float* __restrict__ xyz1, const float* __restrict__ xyz2,
        const float4* __restrict__ pk1, const float4* __restrict__ pk2,
        float* __restrict__ out, int N, int M, int blocks_dir0) {
    __shared__ float4 s[CHUNK];
    int bid = blockIdx.x;
    const int dir = (bid >= blocks_dir0) ? 1 : 0;
    if (dir) bid -= blocks_dir0;
    const int Nsrc = dir ? M : N;
    const int Mdst = dir ? N : M;
    const float* src   = dir ? xyz2 : xyz1;
    const float4* dstp = dir ? pk1  : pk2;
    float* outd        = dir ? (out + (size_t)BATCH * N) : out;
    const int YT = Nsrc / (TPB * P);
    const int Z  = Mdst / CHUNK;
    const int b  = bid / (YT * Z);
    const int r  = bid % (YT * Z);
    const int yt = r / Z;
    const int z  = r % Z;
    const float4* dchunk = dstp + (size_t)b * Mdst + (size_t)z * CHUNK;
    for (int t = threadIdx.x; t < CHUNK / 2; t += TPB) {
        const float4 q0 = dchunk[2 * t];
        const float4 q1 = dchunk[2 * t + 1];
        s[2 * t]     = make_float4(q0.x, q1.x, q0.y, q1.y);
        s[2 * t + 1] = make_float4(q0.z, q1.z, q0.w, q1.w);
    }
    const int i0 = yt * (TPB * P) + threadIdx.x;
    f32x2 px[P], py[P], pz[P];
    float psq[P], m[P];
    #pragma unroll
    for (int k = 0; k < P; ++k) {
        const int i = i0 + k * TPB;
        const float* p = src + ((size_t)b * Nsrc + i) * 3;
        const float x = p[0], y = p[1], zc = p[2];
        px[k] = (f32x2){x, x}; py[k] = (f32x2){y, y}; pz[k] = (f32x2){zc, zc};
        psq[k] = fmaf(x, x, fmaf(y, y, zc * zc));
        m[k] = FLT_MAX;
    }
    __syncthreads();
    #pragma unroll 8
    for (int jj = 0; jj < CHUNK / 2; ++jj) {
        const float4 A = s[2 * jj];
        const float4 B = s[2 * jj + 1];
        const f32x2 xq = (f32x2){A.x, A.y};
        const f32x2 yq = (f32x2){A.z, A.w};
        const f32x2 zq = (f32x2){B.x, B.y};
        const f32x2 wq = (f32x2){B.z, B.w};
        #pragma unroll
        for (int k = 0; k < P; ++k) {
            const f32x2 e = __builtin_elementwise_fma(xq, px[k],
                             __builtin_elementwise_fma(yq, py[k],
                              __builtin_elementwise_fma(zq, pz[k], wq)));
            m[k] = fminf(fminf(m[k], e.x), e.y);
        }
    }
    #pragma unroll
    for (int k = 0; k < P; ++k) {
        const int i = i0 + k * TPB;
        const float d = fmaxf(psq[k] + m[k], 0.0f);
        atomicMin((int*)&outd[(size_t)b * Nsrc + i], __float_as_int(d));
    }
}

extern "C" void kernel_launch(void* const* d_in, const int* in_sizes, int n_in,
                              void* d_out, int out_size, void* d_ws, size_t ws_size,
                              hipStream_t stream) {
    const float* xyz1 = (const float*)d_in[0];
    const float* xyz2 = (const float*)d_in[1];
    float* out = (float*)d_out;

    const int N = in_sizes[0] / (BATCH * 3);  // 8192
    const int M = in_sizes[1] / (BATCH * 3);  // 8192
    const int n1 = BATCH * N, n2 = BATCH * M;

    constexpr int TPB = 256;
    constexpr int NJ = 8;

    const size_t need16 = ((size_t)n1 + (size_t)n2) * 64;  // A+B fp16 forms
    const bool mfma_ok = (N == M) && (N % (NJ * 256) == 0) && (ws_size >= need16);

    if (mfma_ok) {
        _Float16* pa1 = (_Float16*)d_ws;
        _Float16* pb1 = pa1 + (size_t)n1 * 16;
        _Float16* pa2 = pb1 + (size_t)n1 * 16;
        _Float16* pb2 = pa2 + (size_t)n2 * 16;
        int prep_n = out_size > n1 ? out_size : n1;
        if (n2 > prep_n) prep_n = n2;
        prep_fp16<<<(prep_n + TPB - 1) / TPB, TPB, 0, stream>>>(
            xyz1, xyz2, pa1, pb1, pa2, pb2, out, n1, n2, out_size);

        const int grid = 2 * BATCH * (N / 256) * NJ;   // 2048
        chamfer_mfma32<NJ><<<grid, TPB, 0, stream>>>(pa1, pb1, pa2, pb2, out, N);
        return;
    }

    // fallback: R6 pk-fma path
    constexpr int CHUNK = 128;
    constexpr int P = 8;
    const size_t need = ((size_t)n1 + (size_t)n2) * sizeof(float4);
    if (ws_size >= need && (N % (TPB * P) == 0) && (M % (TPB * P) == 0) &&
        (N % CHUNK == 0) && (M % CHUNK == 0)) {
        float4* pk1 = (float4*)d_ws;
        float4* pk2 = pk1 + n1;
        int prep_n = out_size > n1 ? out_size : n1;
        if (n2 > prep_n) prep_n = n2;
        chamfer_prep<<<(prep_n + TPB - 1) / TPB, TPB, 0, stream>>>(
            xyz1, xyz2, pk1, pk2, out, n1, n2, out_size);
        const int blocks_dir0 = BATCH * (N / (TPB * P)) * (M / CHUNK);
        const int blocks_dir1 = BATCH * (M / (TPB * P)) * (N / CHUNK);
        chamfer_fused<TPB, CHUNK, P><<<blocks_dir0 + blocks_dir1, TPB, 0, stream>>>(
            xyz1, xyz2, pk1, pk2, out, N, M, blocks_dir0);
    }
}

// Round 11
// 36.501 us; speedup vs baseline: 16.4309x; 2.1447x over previous
//
#include <hip/hip_runtime.h>
#include <float.h>

#define BATCH 4

typedef _Float16 half8 __attribute__((ext_vector_type(8)));
typedef float f32x16 __attribute__((ext_vector_type(16)));
typedef float f32x2 __attribute__((ext_vector_type(2)));

// ================= MFMA path =================
// D[p,q] = |p|^2 + |q|^2 - 2 p.q  via K=13 fp16 slots (exact split):
//  A[p] = [hx,hy,hz, hx,hy,hz, ex,ey,ez, ps_h, ps_e, 1, 1, 0,0,0]
//  B[q] = [-2hx,-2hy,-2hz, -2ex,-2ey,-2ez, -2hx,-2hy,-2hz, 1, 1, qs_h, qs_e, 0,0,0]
// fp16*fp16 products exact in fp32 accumulator. Verified R7-R10: absmax 4e-3.
// Role-symmetric: A rows = dst (scan) points, B cols = src (owned) points.

__global__ void prep_fp16(const float* __restrict__ x1, const float* __restrict__ x2,
                          _Float16* __restrict__ pa1, _Float16* __restrict__ pb1,
                          _Float16* __restrict__ pa2, _Float16* __restrict__ pb2,
                          float* __restrict__ out, int n1, int n2, int outn) {
    const int i = blockIdx.x * blockDim.x + threadIdx.x;
    const _Float16 one = (_Float16)1.0f, zro = (_Float16)0.0f;

    #pragma unroll
    for (int which = 0; which < 2; ++which) {
        const int n = which ? n2 : n1;
        if (i >= n) continue;
        const float* xp = (which ? x2 : x1) + 3 * (size_t)i;
        _Float16* pa = (which ? pa2 : pa1) + 16 * (size_t)i;
        _Float16* pb = (which ? pb2 : pb1) + 16 * (size_t)i;

        const float x = xp[0], y = xp[1], z = xp[2];
        const _Float16 hx = (_Float16)x, hy = (_Float16)y, hz = (_Float16)z;
        const _Float16 ex = (_Float16)(x - (float)hx);
        const _Float16 ey = (_Float16)(y - (float)hy);
        const _Float16 ez = (_Float16)(z - (float)hz);
        const float ps = fmaf(x, x, fmaf(y, y, z * z));
        const _Float16 ph = (_Float16)ps;
        const _Float16 pe = (_Float16)(ps - (float)ph);
        const _Float16 tx = (_Float16)(-2.0f * (float)hx);
        const _Float16 ty = (_Float16)(-2.0f * (float)hy);
        const _Float16 tz = (_Float16)(-2.0f * (float)hz);
        const _Float16 ux = (_Float16)(-2.0f * (float)ex);
        const _Float16 uy = (_Float16)(-2.0f * (float)ey);
        const _Float16 uz = (_Float16)(-2.0f * (float)ez);

        const half8 a0 = (half8){hx, hy, hz, hx, hy, hz, ex, ey};
        const half8 a1 = (half8){ez, ph, pe, one, one, zro, zro, zro};
        const half8 b0 = (half8){tx, ty, tz, ux, uy, uz, tx, ty};
        const half8 b1 = (half8){tz, one, one, ph, pe, zro, zro, zro};

        *(half8*)(pa)     = a0;   // 16B vector stores
        *(half8*)(pa + 8) = a1;
        *(half8*)(pb)     = b0;
        *(half8*)(pb + 8) = b1;
    }
    if (i < outn) out[i] = FLT_MAX;
}

// min of 16 floats via v_min3_f32 tree (8 instructions).
__device__ inline float min16(const f32x16 d) {
    const float t0 = fminf(fminf(d[0],  d[1]),  d[2]);
    const float t1 = fminf(fminf(d[3],  d[4]),  d[5]);
    const float t2 = fminf(fminf(d[6],  d[7]),  d[8]);
    const float t3 = fminf(fminf(d[9],  d[10]), d[11]);
    const float t4 = fminf(fminf(d[12], d[13]), d[14]);
    const float u0 = fminf(fminf(t0, t1), t2);
    const float u1 = fminf(fminf(t3, t4), d[15]);
    return fminf(u0, u1);
}

// Block: 4 waves x IT=2 src-tiles of 32 cols = 256 src points per block.
// Sweeps a j-segment (N/NJ dst points) in LDS stages of 256 = 8 A-tiles.
// KEY (vs R10): src points are the MFMA *B* operand -> every lane's 16 D
// elements belong to its own src point (col = lane&31); min over the scan
// dim is an in-register min3 tree into ONE scalar rmin[it] per lane. No
// f32x16 accumulators, no DPP epilogue -> low VGPR -> high occupancy.
// NOTE: plain __launch_bounds__(256) — R5/R9: any min-waves arg register-
// starves this kernel family and spills f32x16 temps to scratch.
// Layouts (verified R8/R10):
//  A/B frag: row/col = lane&31, k-half = lane>>5 (8 contiguous f16 = 16B)
//  D: col = lane&31 (src i), row = (e&3)+8*(e>>2)+4*(lane>>5) (dst j)
template<int NJ>
__global__ __launch_bounds__(256) void chamfer_mfma32(
        const _Float16* __restrict__ pa1, const _Float16* __restrict__ pb1,
        const _Float16* __restrict__ pa2, const _Float16* __restrict__ pb2,
        float* __restrict__ out, int N) {
    constexpr int IT = 2;
    __shared__ uint4 sA[512];   // 8 dst-tiles * 64 frag-slots * 16B = 8 KiB

    const int tid  = threadIdx.x;
    const int lane = tid & 63;
    const int w    = tid >> 6;

    int bid = blockIdx.x;
    const int RB      = N / 256;
    const int per_dir = BATCH * RB * NJ;
    const int dir = bid / per_dir;   bid %= per_dir;
    const int b   = bid / (RB * NJ); bid %= (RB * NJ);
    const int cb  = bid / NJ;        // src col-block
    const int js  = bid % NJ;        // dst segment

    // dir0: src=set1 (held B-form), scan dst=set2 (staged A-form)
    const _Float16* pstage = dir ? pa1 : pa2;
    const _Float16* pheld  = dir ? pb2 : pb1;
    float* outd = out + (size_t)dir * BATCH * N + (size_t)b * N;

    // Held src B-fragments: 16B per lane.
    const int colbase = cb * 256 + w * 64;
    const uint4* gh = (const uint4*)pheld;
    half8 bf[IT];
    #pragma unroll
    for (int it = 0; it < IT; ++it) {
        const int c = colbase + it * 32 + (lane & 31);
        bf[it] = __builtin_bit_cast(half8, gh[(size_t)(b * N + c) * 2 + (lane >> 5)]);
    }

    float rmin[IT];
    #pragma unroll
    for (int it = 0; it < IT; ++it) rmin[it] = FLT_MAX;

    f32x16 cz;
    #pragma unroll
    for (int e = 0; e < 16; ++e) cz[e] = 0.0f;

    const int jseg   = N / NJ;
    const int stages = jseg / 256;
    const uint4* gs  = (const uint4*)pstage;
    const int t = tid >> 5, col = tid & 31;

    for (int s = 0; s < stages; ++s) {
        // stage 256 dst points (32B each) into LDS
        const size_t q = (size_t)(b * N + js * jseg + s * 256 + tid) * 2;
        const uint4 v0 = gs[q];
        const uint4 v1 = gs[q + 1];
        __syncthreads();                 // prior stage fully consumed
        sA[t * 64 + col]      = v0;      // k 0..7  -> lanes 0..31
        sA[t * 64 + 32 + col] = v1;      // k 8..15 -> lanes 32..63
        __syncthreads();

        #pragma unroll
        for (int p = 0; p < 8; ++p) {
            const half8 a = __builtin_bit_cast(half8, sA[p * 64 + lane]);
            #pragma unroll
            for (int it = 0; it < IT; ++it) {
                const f32x16 d = __builtin_amdgcn_mfma_f32_32x32x16_f16(a, bf[it], cz, 0, 0, 0);
                rmin[it] = fminf(rmin[it], min16(d));
            }
        }
    }

    // epilogue: combine row-halves (lane L holds rows {..}, L^32 the rest)
    #pragma unroll
    for (int it = 0; it < IT; ++it) {
        float v = fminf(rmin[it], __shfl_xor(rmin[it], 32, 64));
        v = fmaxf(v, 0.0f);              // >=0 keeps int-punned min ordering
        if (lane < 32)
            atomicMin((int*)&outd[colbase + it * 32 + lane], __float_as_int(v));
    }
}

// ================= fallback: R6 pk-fma path =================
__global__ void chamfer_prep(const float* __restrict__ xyz1,
                             const float* __restrict__ xyz2,
                             float4* __restrict__ pk1,
                             float4* __restrict__ pk2,
                             float* __restrict__ out,
                             int n1, int n2, int out_n) {
    int i = blockIdx.x * blockDim.x + threadIdx.x;
    if (i < n1) {
        float x = xyz1[3 * (size_t)i], y = xyz1[3 * (size_t)i + 1], z = xyz1[3 * (size_t)i + 2];
        pk1[i] = make_float4(-2.f * x, -2.f * y, -2.f * z, fmaf(x, x, fmaf(y, y, z * z)));
    }
    if (i < n2) {
        float x = xyz2[3 * (size_t)i], y = xyz2[3 * (size_t)i + 1], z = xyz2[3 * (size_t)i + 2];
        pk2[i] = make_float4(-2.f * x, -2.f * y, -2.f * z, fmaf(x, x, fmaf(y, y, z * z)));
    }
    if (i < out_n) out[i] = FLT_MAX;
}

template<int TPB, int CHUNK, int P>
__global__ __launch_bounds__(TPB) void chamfer_fused(
        const float* __restrict__ xyz1, const float* __restrict__ xyz2,
        const float4* __restrict__ pk1, const float4* __restrict__ pk2,
        float* __restrict__ out, int N, int M, int blocks_dir0) {
    __shared__ float4 s[CHUNK];
    int bid = blockIdx.x;
    const int dir = (bid >= blocks_dir0) ? 1 : 0;
    if (dir) bid -= blocks_dir0;
    const int Nsrc = dir ? M : N;
    const int Mdst = dir ? N : M;
    const float* src   = dir ? xyz2 : xyz1;
    const float4* dstp = dir ? pk1  : pk2;
    float* outd        = dir ? (out + (size_t)BATCH * N) : out;
    const int YT = Nsrc / (TPB * P);
    const int Z  = Mdst / CHUNK;
    const int b  = bid / (YT * Z);
    const int r  = bid % (YT * Z);
    const int yt = r / Z;
    const int z  = r % Z;
    const float4* dchunk = dstp + (size_t)b * Mdst + (size_t)z * CHUNK;
    for (int t = threadIdx.x; t < CHUNK / 2; t += TPB) {
        const float4 q0 = dchunk[2 * t];
        const float4 q1 = dchunk[2 * t + 1];
        s[2 * t]     = make_float4(q0.x, q1.x, q0.y, q1.y);
        s[2 * t + 1] = make_float4(q0.z, q1.z, q0.w, q1.w);
    }
    const int i0 = yt * (TPB * P) + threadIdx.x;
    f32x2 px[P], py[P], pz[P];
    float psq[P], m[P];
    #pragma unroll
    for (int k = 0; k < P; ++k) {
        const int i = i0 + k * TPB;
        const float* p = src + ((size_t)b * Nsrc + i) * 3;
        const float x = p[0], y = p[1], zc = p[2];
        px[k] = (f32x2){x, x}; py[k] = (f32x2){y, y}; pz[k] = (f32x2){zc, zc};
        psq[k] = fmaf(x, x, fmaf(y, y, zc * zc));
        m[k] = FLT_MAX;
    }
    __syncthreads();
    #pragma unroll 8
    for (int jj = 0; jj < CHUNK / 2; ++jj) {
        const float4 A = s[2 * jj];
        const float4 B = s[2 * jj + 1];
        const f32x2 xq = (f32x2){A.x, A.y};
        const f32x2 yq = (f32x2){A.z, A.w};
        const f32x2 zq = (f32x2){B.x, B.y};
        const f32x2 wq = (f32x2){B.z, B.w};
        #pragma unroll
        for (int k = 0; k < P; ++k) {
            const f32x2 e = __builtin_elementwise_fma(xq, px[k],
                             __builtin_elementwise_fma(yq, py[k],
                              __builtin_elementwise_fma(zq, pz[k], wq)));
            m[k] = fminf(fminf(m[k], e.x), e.y);
        }
    }
    #pragma unroll
    for (int k = 0; k < P; ++k) {
        const int i = i0 + k * TPB;
        const float d = fmaxf(psq[k] + m[k], 0.0f);
        atomicMin((int*)&outd[(size_t)b * Nsrc + i], __float_as_int(d));
    }
}

extern "C" void kernel_launch(void* const* d_in, const int* in_sizes, int n_in,
                              void* d_out, int out_size, void* d_ws, size_t ws_size,
                              hipStream_t stream) {
    const float* xyz1 = (const float*)d_in[0];
    const float* xyz2 = (const float*)d_in[1];
    float* out = (float*)d_out;

    const int N = in_sizes[0] / (BATCH * 3);  // 8192
    const int M = in_sizes[1] / (BATCH * 3);  // 8192
    const int n1 = BATCH * N, n2 = BATCH * M;

    constexpr int TPB = 256;
    constexpr int NJ = 8;

    const size_t need16 = ((size_t)n1 + (size_t)n2) * 64;  // A+B fp16 forms
    const bool mfma_ok = (N == M) && (N % (NJ * 256) == 0) && (ws_size >= need16);

    if (mfma_ok) {
        _Float16* pa1 = (_Float16*)d_ws;
        _Float16* pb1 = pa1 + (size_t)n1 * 16;
        _Float16* pa2 = pb1 + (size_t)n1 * 16;
        _Float16* pb2 = pa2 + (size_t)n2 * 16;
        int prep_n = out_size > n1 ? out_size : n1;
        if (n2 > prep_n) prep_n = n2;
        prep_fp16<<<(prep_n + TPB - 1) / TPB, TPB, 0, stream>>>(
            xyz1, xyz2, pa1, pb1, pa2, pb2, out, n1, n2, out_size);

        const int grid = 2 * BATCH * (N / 256) * NJ;   // 2048
        chamfer_mfma32<NJ><<<grid, TPB, 0, stream>>>(pa1, pb1, pa2, pb2, out, N);
        return;
    }

    // fallback: R6 pk-fma path
    constexpr int CHUNK = 128;
    constexpr int P = 8;
    const size_t need = ((size_t)n1 + (size_t)n2) * sizeof(float4);
    if (ws_size >= need && (N % (TPB * P) == 0) && (M % (TPB * P) == 0) &&
        (N % CHUNK == 0) && (M % CHUNK == 0)) {
        float4* pk1 = (float4*)d_ws;
        float4* pk2 = pk1 + n1;
        int prep_n = out_size > n1 ? out_size : n1;
        if (n2 > prep_n) prep_n = n2;
        chamfer_prep<<<(prep_n + TPB - 1) / TPB, TPB, 0, stream>>>(
            xyz1, xyz2, pk1, pk2, out, n1, n2, out_size);
        const int blocks_dir0 = BATCH * (N / (TPB * P)) * (M / CHUNK);
        const int blocks_dir1 = BATCH * (M / (TPB * P)) * (N / CHUNK);
        chamfer_fused<TPB, CHUNK, P><<<blocks_dir0 + blocks_dir1, TPB, 0, stream>>>(
            xyz1, xyz2, pk1, pk2, out, N, M, blocks_dir0);
    }
}